// Round 7
// baseline (580.253 us; speedup 1.0000x reference)
//
#include <hip/hip_runtime.h>

#define NB 32      // batches
#define MM 448
#define CC 384
#define SS 512
#define KNN 8
#define NBLK 512u  // fused-kernel grid; co-residency proven (R2/R3/R4/R6 barriers converged)

// workspace byte offsets — 8KB guard gaps between cross-phase buffers
#define WS_IDX    0u            // int   idx[32][512][8]   = 512 KB
#define WS_H1     524288u       // float h1[32][512][64]   = 4 MB   (ends 4718592)
#define WS_PMAX   4726784u      // float pmax[32*16][128]  = 256 KB (ends 4988928)
#define WS_BASEP  4997120u      // float basep[32][384]    = 48 KB  (ends 5046272)
#define WS_BAR    5054464u      // unsigned bar[8*32]      = 1 KB

#define AGENT __HIP_MEMORY_SCOPE_AGENT

// Cross-phase WRITES: sc0/sc1 bypass stores -> coherent at IF, never dirty any
// per-XCD L2 (proven R3/R6). Readers use normal cached vectorized loads
// (proven R4/R6): no stale pre-write line can exist.
__device__ __forceinline__ void stg_f(float* p, float v) {
  __hip_atomic_store(p, v, __ATOMIC_RELAXED, AGENT);
}

// Fence-free device barrier (R3/R6-proven). release = per-wave vmcnt drain;
// arrival = relaxed RMW on 8 split counters; wait = self-sum poll; NO threadfence.
__device__ __forceinline__ void gbar(unsigned* bar, int phase, int blk) {
  asm volatile("s_waitcnt vmcnt(0)" ::: "memory");
  __syncthreads();
  if (threadIdx.x == 0) {
    __hip_atomic_fetch_add(bar + (blk & 7) * 32, 1u, __ATOMIC_RELAXED, AGENT);
    const unsigned target = NBLK * (unsigned)(phase + 1);
    long spins = 0;
    for (;;) {
      unsigned s = 0;
#pragma unroll
      for (int i = 0; i < 8; i++)
        s += __hip_atomic_load(bar + i * 32, __ATOMIC_RELAXED, AGENT);
      if (s >= target) break;
      __builtin_amdgcn_s_sleep(2);
      if (++spins > (1L << 18)) break;   // failsafe: bounded wrong answer, never a hang
    }
  }
  __syncthreads();
}

// ------------------------------------------------- K1: KNN + gc1, wave-per-point
__global__ __launch_bounds__(256) void k_knn_gc1(
    const float* __restrict__ skel,
    const float* __restrict__ w1root, const float* __restrict__ w1rel,
    const float* __restrict__ b1,
    int* __restrict__ idx_ws, float* __restrict__ h1_ws,
    unsigned* __restrict__ bar)
{
  // re-arm the fused kernel's barrier counters every launch (bypass stores)
  if (blockIdx.x == 0 && threadIdx.x < 8)
    __hip_atomic_store(&bar[threadIdx.x * 32], 0u, __ATOMIC_RELAXED, AGENT);

  int b   = blockIdx.x >> 7;          // 128 groups of 4 points per batch
  int grp = blockIdx.x & 127;
  __shared__ __align__(16) float4 sk[SS];
  const float* sb = skel + b * SS * 3;
  for (int t = threadIdx.x; t < SS; t += 256)
    sk[t] = make_float4(sb[t*3+0], sb[t*3+1], sb[t*3+2], 0.f);
  __syncthreads();

  int wave = threadIdx.x >> 6, lane = threadIdx.x & 63;
  int i = grp * 4 + wave;             // this wave's point
  float4 pi = sk[i];

  float bd[KNN];
#pragma unroll
  for (int t = 0; t < KNN; t++) {
    int j = lane + (t << 6);
    float4 p = sk[j];
    float d2;
    {
#pragma clang fp contract(off)
      float dx = pi.x - p.x, dy = pi.y - p.y, dz = pi.z - p.z;
      d2 = (dx*dx + dy*dy) + dz*dz;
    }
    bd[t] = (j == i) ? 3e38f : d2;
  }

  int win[KNN];
  int* idx_base = idx_ws + (size_t)(b*SS + i) * KNN;
#pragma unroll
  for (int t = 0; t < KNN; t++) {
    float bestd = bd[0]; int bests = 0;
#pragma unroll
    for (int s = 1; s < KNN; s++)
      if (bd[s] < bestd) { bestd = bd[s]; bests = s; }
    int bestj = lane + (bests << 6);
#pragma unroll
    for (int m = 1; m < 64; m <<= 1) {
      float od = __shfl_xor(bestd, m, 64);
      int   oj = __shfl_xor(bestj, m, 64);
      if (od < bestd || (od == bestd && oj < bestj)) { bestd = od; bestj = oj; }
    }
    win[t] = bestj;
    if (lane == t) idx_base[t] = bestj;
    if ((bestj & 63) == lane) {
      int sl = bestj >> 6;
#pragma unroll
      for (int s = 0; s < KNN; s++) if (s == sl) bd[s] = 3e38f;
    }
  }

  float a0 = 0.f, a1 = 0.f, a2 = 0.f;
#pragma unroll
  for (int t = 0; t < KNN; t++) {
    float4 n = sk[win[t]];
    a0 += n.x; a1 += n.y; a2 += n.z;
  }

  int c = lane;
  float h = b1[c] + pi.x*w1root[c] + pi.y*w1root[64+c] + pi.z*w1root[128+c]
                  + a0*w1rel[c]   + a1*w1rel[64+c]   + a2*w1rel[128+c];
  h = fmaxf(h, 0.f);
  h1_ws[(size_t)(b*SS + i) * 64 + lane] = h;
}

// ===== K2: everything after KNN+gc1 — 3 phases, 2 device barriers
struct CoopArgs {
  const float* h1; const int* idx;
  const float *g2wr, *g2wl, *g2b;
  const float *projw, *projb;
  const float *aiw, *aib, *aow, *aob;
  const float *i1w, *i1b, *bng, *bnb, *bnm, *bnv;
  const float *i2w, *i2b;
  const float *redw, *redb;
  const float* coarse;
  float *pmax, *basep, *out;
  unsigned* bar;
};

__global__ __launch_bounds__(256, 2) void k_fused(CoopArgs a)
{
  __shared__ __align__(16) float smem[9600];   // 38.4 KB (gc2 union)
  const int t   = threadIdx.x;
  const int blk = blockIdx.x;

  // ---------------- phase 1: gc2 + per-chunk max (512 blocks) ----------------
  {
    int b = blk >> 4, chunk = blk & 15;
    int r0 = chunk * 32;
    float* X    = smem;                  // [32][129]
    float* Wt   = smem + 4128;           // [32][128]
    float* mred = smem + 8224;           // [8][128]
    int*   nbs  = (int*)(smem + 9248);   // [32][8]

    const float* h1b = a.h1 + (size_t)b * SS * 64;
    nbs[t] = a.idx[(b*SS + r0)*KNN + t];
#pragma unroll
    for (int p = 0; p < 8; p++) {
      int idx = t + 256*p;
      int r = idx >> 6, k = idx & 63;
      X[r*129 + k] = h1b[(r0 + r)*64 + k];
    }
    __syncthreads();   // nbs ready
#pragma unroll
    for (int p = 0; p < 8; p++) {
      int idx = t + 256*p;
      int r = idx >> 6, k = idx & 63;
      const int* nb = nbs + r*KNN;
      float s = 0.f;
#pragma unroll
      for (int j = 0; j < KNN; j++) s += h1b[nb[j]*64 + k];
      X[r*129 + 64 + k] = s;
    }

    int rg = t >> 5, cgi = t & 31;
    float acc[4][4];
#pragma unroll
    for (int r = 0; r < 4; r++)
#pragma unroll
      for (int u = 0; u < 4; u++) acc[r][u] = 0.f;

    const float* wsrc[4] = { a.g2wr, a.g2wr + 32*128, a.g2wl, a.g2wl + 32*128 };
#pragma unroll 1
    for (int ch = 0; ch < 4; ch++) {
      __syncthreads();
      const float* ws = wsrc[ch];
#pragma unroll
      for (int p = 0; p < 16; p++) {
        int idx = t + 256*p;
        Wt[idx] = ws[idx];
      }
      __syncthreads();
      int kb = ch * 32;
      const float* xr0 = X + (rg*4+0)*129 + kb;
      const float* xr1 = X + (rg*4+1)*129 + kb;
      const float* xr2 = X + (rg*4+2)*129 + kb;
      const float* xr3 = X + (rg*4+3)*129 + kb;
#pragma unroll 4
      for (int k = 0; k < 32; k++) {
        float4 w4 = *(const float4*)(Wt + k*128 + cgi*4);
        float x0 = xr0[k], x1 = xr1[k], x2 = xr2[k], x3 = xr3[k];
        acc[0][0] += x0*w4.x; acc[0][1] += x0*w4.y; acc[0][2] += x0*w4.z; acc[0][3] += x0*w4.w;
        acc[1][0] += x1*w4.x; acc[1][1] += x1*w4.y; acc[1][2] += x1*w4.z; acc[1][3] += x1*w4.w;
        acc[2][0] += x2*w4.x; acc[2][1] += x2*w4.y; acc[2][2] += x2*w4.z; acc[2][3] += x2*w4.w;
        acc[3][0] += x3*w4.x; acc[3][1] += x3*w4.y; acc[3][2] += x3*w4.z; acc[3][3] += x3*w4.w;
      }
    }
#pragma unroll
    for (int u = 0; u < 4; u++)
      mred[rg*128 + cgi*4 + u] =
        fmaxf(fmaxf(acc[0][u], acc[1][u]), fmaxf(acc[2][u], acc[3][u]));
    __syncthreads();
    if (t < 128) {
      float mx = mred[t];
#pragma unroll
      for (int g = 1; g < 8; g++) mx = fmaxf(mx, mred[g*128 + t]);
      stg_f(&a.pmax[(size_t)(b*16 + chunk)*128 + t], mx + a.g2b[t]);
    }
  }
  gbar(a.bar, 0, blk);

  // --- phase 2: per-batch chain proxy->kv->vv->q->inc1->inc2->basep (32 blks)
  // All activations LDS-resident; only basep leaves the block (bypass stores).
  if (blk < NB) {
    int b = blk;
    float* proxy = smem;            // [128]
    float* kv    = smem + 128;      // [384]
    float* vvv   = smem + 512;      // [384]
    float* qv    = smem + 896;      // [384]
    float* yy    = smem + 1280;     // [1024]
    float* g2    = smem + 2304;     // [1024]  (3328 floats = 13.3 KB)

    if (t < 128) {
      float m = -3e38f;
      const float* pm = a.pmax + (size_t)b*2048 + t;
#pragma unroll
      for (int ch = 0; ch < 16; ch++) m = fmaxf(m, pm[ch*128]);
      proxy[t] = m;
    }
    __syncthreads();
    // kv = proxy @ projw + projb      (projw [128][384], o-coalesced)
    for (int o = t; o < CC; o += 256) {
      float acc = a.projb[o];
#pragma unroll 8
      for (int k = 0; k < 128; k++) acc += proxy[k] * a.projw[k*CC + o];
      kv[o] = acc;
    }
    __syncthreads();
    // vv = kv @ wv.T + bv             (row-major rows, per-thread float4)
    for (int o = t; o < CC; o += 256) {
      const float4* w4 = (const float4*)(a.aiw + (size_t)(2*CC + o) * CC);
      const float4* x4 = (const float4*)kv;
      float acc = a.aib[2*CC + o];
#pragma unroll 8
      for (int k = 0; k < CC/4; k++) {
        float4 xv = x4[k], wv = w4[k];
        acc += xv.x*wv.x + xv.y*wv.y + xv.z*wv.z + xv.w*wv.w;
      }
      vvv[o] = acc;
    }
    __syncthreads();
    // q = vv @ aow.T + aob
    for (int o = t; o < CC; o += 256) {
      const float4* w4 = (const float4*)(a.aow + (size_t)o * CC);
      const float4* x4 = (const float4*)vvv;
      float acc = a.aob[o];
#pragma unroll 8
      for (int k = 0; k < CC/4; k++) {
        float4 xv = x4[k], wv = w4[k];
        acc += xv.x*wv.x + xv.y*wv.y + xv.z*wv.z + xv.w*wv.w;
      }
      qv[o] = acc;
    }
    __syncthreads();
    // y = leaky(BN(inc1(q)))
    for (int o = t; o < 1024; o += 256) {
      const float4* w4 = (const float4*)(a.i1w + (size_t)o * CC);
      const float4* x4 = (const float4*)qv;
      float acc = a.i1b[o];
#pragma unroll 8
      for (int k = 0; k < CC/4; k++) {
        float4 xv = x4[k], wv = w4[k];
        acc += xv.x*wv.x + xv.y*wv.y + xv.z*wv.z + xv.w*wv.w;
      }
      float z = a.bng[o] * (acc - a.bnm[o]) * rsqrtf(a.bnv[o] + 1e-5f) + a.bnb[o];
      yy[o] = (z >= 0.f) ? z : 0.2f * z;
    }
    __syncthreads();
    // g2 = inc2(y)
    for (int o = t; o < 1024; o += 256) {
      const float4* w4 = (const float4*)(a.i2w + (size_t)o * 1024);
      const float4* x4 = (const float4*)yy;
      float acc = a.i2b[o];
#pragma unroll 8
      for (int k = 0; k < 1024/4; k++) {
        float4 xv = x4[k], wv = w4[k];
        acc += xv.x*wv.x + xv.y*wv.y + xv.z*wv.z + xv.w*wv.w;
      }
      g2[o] = acc;
    }
    __syncthreads();
    // basep = [g2 | q] @ red_w[:1408]   (redw [k][384], o-coalesced)
    for (int o = t; o < CC; o += 256) {
      float acc = 0.f;
#pragma unroll 4
      for (int k = 0; k < 1024; k++) acc += g2[k] * a.redw[(size_t)k*CC + o];
#pragma unroll 4
      for (int k = 0; k < CC; k++)  acc += qv[k] * a.redw[(size_t)(1024+k)*CC + o];
      stg_f(&a.basep[b*CC + o], acc);
    }
  }
  gbar(a.bar, 1, blk);

  // ----- phase 3: out = basep + red_b + coarse @ red_w[1408:] (512 blocks) ---
  {
    int b = blk >> 4, mg = blk & 15;            // 16 blocks/batch, 28 rows each
    for (int i = t; i < CC; i += 256) smem[i] = a.basep[b*CC + i];
    __syncthreads();
    const int m0 = mg * 28;
    for (int i = t; i < 28*96; i += 256) {
      int mr = i / 96, c4 = i - mr*96;
      int row = b*MM + m0 + mr;
      int c = c4 * 4;
      float4 p0 = *(const float4*)(smem + c);
      float4 rb = *(const float4*)(a.redb + c);
      const float* cr = a.coarse + (size_t)row * 3;
      float cx = cr[0], cy = cr[1], cz = cr[2];
      float4 w0 = *(const float4*)(a.redw + (size_t)1408*CC + c);
      float4 w1 = *(const float4*)(a.redw + (size_t)1409*CC + c);
      float4 w2 = *(const float4*)(a.redw + (size_t)1410*CC + c);
      float4 o4v;
      o4v.x = p0.x + rb.x + cx*w0.x + cy*w1.x + cz*w2.x;
      o4v.y = p0.y + rb.y + cx*w0.y + cy*w1.y + cz*w2.y;
      o4v.z = p0.z + rb.z + cx*w0.z + cy*w1.z + cz*w2.z;
      o4v.w = p0.w + rb.w + cx*w0.w + cy*w1.w + cz*w2.w;
      *(float4*)(a.out + (size_t)row*CC + c) = o4v;
    }
  }
}

extern "C" void kernel_launch(void* const* d_in, const int* in_sizes, int n_in,
                              void* d_out, int out_size, void* d_ws, size_t ws_size,
                              hipStream_t stream)
{
  (void)in_sizes; (void)n_in; (void)out_size; (void)ws_size;
  // d_in[0] is q (B,M,C): provably unused — attention softmax is uniform.
  const float* coarse = (const float*)d_in[1];
  const float* skel   = (const float*)d_in[2];
  const float* g1wr   = (const float*)d_in[3];
  const float* g1wl   = (const float*)d_in[4];
  const float* g1b    = (const float*)d_in[5];

  char* ws = (char*)d_ws;
  int*      idx_ws = (int*)(ws + WS_IDX);
  float*    h1_ws  = (float*)(ws + WS_H1);
  unsigned* bar    = (unsigned*)(ws + WS_BAR);

  CoopArgs a;
  a.h1    = h1_ws;
  a.idx   = idx_ws;
  a.g2wr  = (const float*)d_in[6];
  a.g2wl  = (const float*)d_in[7];
  a.g2b   = (const float*)d_in[8];
  a.projw = (const float*)d_in[9];
  a.projb = (const float*)d_in[10];
  a.aiw   = (const float*)d_in[11];
  a.aib   = (const float*)d_in[12];
  a.aow   = (const float*)d_in[13];
  a.aob   = (const float*)d_in[14];
  a.i1w   = (const float*)d_in[15];
  a.i1b   = (const float*)d_in[16];
  a.bng   = (const float*)d_in[17];
  a.bnb   = (const float*)d_in[18];
  a.bnm   = (const float*)d_in[19];
  a.bnv   = (const float*)d_in[20];
  a.i2w   = (const float*)d_in[21];
  a.i2b   = (const float*)d_in[22];
  a.redw  = (const float*)d_in[23];
  a.redb  = (const float*)d_in[24];
  a.coarse= coarse;
  a.pmax  = (float*)(ws + WS_PMAX);
  a.basep = (float*)(ws + WS_BASEP);
  a.out   = (float*)d_out;
  a.bar   = bar;

  k_knn_gc1<<<4096, 256, 0, stream>>>(skel, g1wr, g1wl, g1b, idx_ws, h1_ws, bar);
  k_fused<<<NBLK, 256, 0, stream>>>(a);
}

// Round 9
// 334.193 us; speedup vs baseline: 1.7363x; 1.7363x over previous
//
#include <hip/hip_runtime.h>

#define NB 32      // batches
#define MM 448
#define CC 384
#define SS 512
#define KNN 8
#define NBLK 512u  // fused-kernel grid; co-residency proven (R2/R3/R4/R6/R7 barriers converged)

// workspace byte offsets — 8KB guard gaps between all cross-phase buffers
#define WS_IDX    0u            // int   idx[32][512][8]   = 512 KB
#define WS_H1     524288u       // float h1[32][512][64]   = 4 MB   (ends 4718592)
#define WS_PMAX   4726784u      // float pmax[32*16][128]  = 256 KB (ends 4988928)
#define WS_KV     4997120u      // float kv[32][384]       = 48 KB  (ends 5046272)
#define WS_VV     5054464u      // float vv[32][384]       = 48 KB  (ends 5103616)
#define WS_Y      5111808u      // float y[32][1024]       = 128 KB (ends 5242880)
#define WS_XCAT   5251072u      // float xcat[32][1408]    = 176 KB (ends 5431296)
#define WS_BASEP  5439488u      // float basep[32][384]    = 48 KB  (ends 5488640)
#define WS_BAR    5496832u      // unsigned bar[128*32]    = 16 KB (64 counters + 64 go, 128B apart)

#define AGENT __HIP_MEMORY_SCOPE_AGENT

// Cross-phase WRITES: sc0/sc1 bypass stores -> coherent at IF, never dirty any
// per-XCD L2 (proven R3/R6/R7). Readers use normal cached vectorized loads
// (proven R4/R6/R7): no stale pre-write line can exist.
__device__ __forceinline__ void stg_f(float* p, float v) {
  __hip_atomic_store(p, v, __ATOMIC_RELAXED, AGENT);
}

// Contention-free device barrier (R8 design; s_sleep args now literal consts).
//  release : per-wave vmcnt drain (bypass stores already at IF when drained)
//  arrival : relaxed RMW on counter line (blk&63) -> <=8 writers/line
//  detect  : block 0 wave-0 only — lane l polls counter l (1 reader/line),
//            shfl-sum, compare against NBLK*(phase+1) (monotonic, no reset)
//  bcast   : block 0 lanes write 64 go-words; waiter leader polls go[blk&63]
//            (<=8 readers/line) with two-stage constant s_sleep backoff
__device__ __forceinline__ void gbar(unsigned* bar, int phase, int blk) {
  asm volatile("s_waitcnt vmcnt(0)" ::: "memory");
  __syncthreads();
  const unsigned tgt = (unsigned)(phase + 1);
  if (threadIdx.x < 64) {                  // wave 0 runs the protocol
    const int lane = threadIdx.x;
    if (lane == 0)
      __hip_atomic_fetch_add(bar + (blk & 63) * 32, 1u, __ATOMIC_RELAXED, AGENT);
    if (blk == 0) {
      long spins = 0;
      for (;;) {
        unsigned s = __hip_atomic_load(bar + lane * 32, __ATOMIC_RELAXED, AGENT);
#pragma unroll
        for (int m = 1; m < 64; m <<= 1) s += __shfl_xor(s, m, 64);
        if (s >= NBLK * tgt) break;
        __builtin_amdgcn_s_sleep(4);
        if (++spins > (1L << 18)) break;   // failsafe: bounded wrong answer, never a hang
      }
      __hip_atomic_store(bar + (64 + lane) * 32, tgt, __ATOMIC_RELAXED, AGENT);
    } else if (lane == 0) {
      long spins = 0;
      while (__hip_atomic_load(bar + (64 + (blk & 63)) * 32,
                               __ATOMIC_RELAXED, AGENT) < tgt) {
        if (spins < 32) __builtin_amdgcn_s_sleep(2);   // fast path: short naps
        else            __builtin_amdgcn_s_sleep(8);   // long-wait: back off
        if (++spins > (1L << 19)) break;   // failsafe
      }
    }
  }
  __syncthreads();
}

// ------------------------------------------------- K1: KNN + gc1, wave-per-point
__global__ __launch_bounds__(256) void k_knn_gc1(
    const float* __restrict__ skel,
    const float* __restrict__ w1root, const float* __restrict__ w1rel,
    const float* __restrict__ b1,
    int* __restrict__ idx_ws, float* __restrict__ h1_ws,
    unsigned* __restrict__ bar)
{
  // re-arm ALL barrier words (64 counters + 64 go) every launch (bypass stores)
  if (blockIdx.x == 0 && threadIdx.x < 128)
    __hip_atomic_store(&bar[threadIdx.x * 32], 0u, __ATOMIC_RELAXED, AGENT);

  int b   = blockIdx.x >> 7;          // 128 groups of 4 points per batch
  int grp = blockIdx.x & 127;
  __shared__ __align__(16) float4 sk[SS];
  const float* sb = skel + b * SS * 3;
  for (int t = threadIdx.x; t < SS; t += 256)
    sk[t] = make_float4(sb[t*3+0], sb[t*3+1], sb[t*3+2], 0.f);
  __syncthreads();

  int wave = threadIdx.x >> 6, lane = threadIdx.x & 63;
  int i = grp * 4 + wave;             // this wave's point
  float4 pi = sk[i];

  float bd[KNN];
#pragma unroll
  for (int t = 0; t < KNN; t++) {
    int j = lane + (t << 6);
    float4 p = sk[j];
    float d2;
    {
#pragma clang fp contract(off)
      float dx = pi.x - p.x, dy = pi.y - p.y, dz = pi.z - p.z;
      d2 = (dx*dx + dy*dy) + dz*dz;
    }
    bd[t] = (j == i) ? 3e38f : d2;
  }

  int win[KNN];
  int* idx_base = idx_ws + (size_t)(b*SS + i) * KNN;
#pragma unroll
  for (int t = 0; t < KNN; t++) {
    float bestd = bd[0]; int bests = 0;
#pragma unroll
    for (int s = 1; s < KNN; s++)
      if (bd[s] < bestd) { bestd = bd[s]; bests = s; }
    int bestj = lane + (bests << 6);
#pragma unroll
    for (int m = 1; m < 64; m <<= 1) {
      float od = __shfl_xor(bestd, m, 64);
      int   oj = __shfl_xor(bestj, m, 64);
      if (od < bestd || (od == bestd && oj < bestj)) { bestd = od; bestj = oj; }
    }
    win[t] = bestj;
    if (lane == t) idx_base[t] = bestj;
    if ((bestj & 63) == lane) {
      int sl = bestj >> 6;
#pragma unroll
      for (int s = 0; s < KNN; s++) if (s == sl) bd[s] = 3e38f;
    }
  }

  float a0 = 0.f, a1 = 0.f, a2 = 0.f;
#pragma unroll
  for (int t = 0; t < KNN; t++) {
    float4 n = sk[win[t]];
    a0 += n.x; a1 += n.y; a2 += n.z;
  }

  int c = lane;
  float h = b1[c] + pi.x*w1root[c] + pi.y*w1root[64+c] + pi.z*w1root[128+c]
                  + a0*w1rel[c]   + a1*w1rel[64+c]   + a2*w1rel[128+c];
  h = fmaxf(h, 0.f);
  h1_ws[(size_t)(b*SS + i) * 64 + lane] = h;
}

// ================ K2: everything after KNN+gc1 — 8 phases, 7 device barriers
// (exact R6 phase structure — only the barrier implementation changed)
struct CoopArgs {
  const float* h1; const int* idx;
  const float *g2wr, *g2wl, *g2b;
  const float *projw, *projb;
  const float *aiw, *aib, *aow, *aob;
  const float *i1w, *i1b, *bng, *bnb, *bnm, *bnv;
  const float *i2w, *i2b;
  const float *redw, *redb;
  const float* coarse;
  float *pmax, *kv, *vv, *y, *xcat, *basep, *out;
  unsigned* bar;
};

// output-split matvec: thread (b = t>>3, oi = t&7) computes out[b][o0+oi].
// Weight rows broadcast 8-way within the wave; cached float4 loads.
__device__ __forceinline__ float matvec8(
    const float* __restrict__ X, int xstride,
    const float* __restrict__ Wrow, int wstride,
    int o, int b, int K4)
{
  const float4* x4 = (const float4*)(X + (size_t)b * xstride);
  const float4* w4 = (const float4*)(Wrow + (size_t)o * wstride);
  float acc = 0.f;
#pragma unroll 4
  for (int k = 0; k < K4; k++) {
    float4 xv = x4[k], wv = w4[k];
    acc += xv.x*wv.x + xv.y*wv.y + xv.z*wv.z + xv.w*wv.w;
  }
  return acc;
}

__global__ __launch_bounds__(256, 2) void k_fused(CoopArgs a)
{
  __shared__ __align__(16) float smem[9600];   // 38.4 KB (gc2 union)
  const int t   = threadIdx.x;
  const int blk = blockIdx.x;

  // ---------------- phase 1: gc2 + per-chunk max (512 blocks) ----------------
  {
    int b = blk >> 4, chunk = blk & 15;
    int r0 = chunk * 32;
    float* X    = smem;                  // [32][129]
    float* Wt   = smem + 4128;           // [32][128]
    float* mred = smem + 8224;           // [8][128]
    int*   nbs  = (int*)(smem + 9248);   // [32][8]

    const float* h1b = a.h1 + (size_t)b * SS * 64;
    nbs[t] = a.idx[(b*SS + r0)*KNN + t];
#pragma unroll
    for (int p = 0; p < 8; p++) {
      int idx = t + 256*p;
      int r = idx >> 6, k = idx & 63;
      X[r*129 + k] = h1b[(r0 + r)*64 + k];
    }
    __syncthreads();   // nbs ready
#pragma unroll
    for (int p = 0; p < 8; p++) {
      int idx = t + 256*p;
      int r = idx >> 6, k = idx & 63;
      const int* nb = nbs + r*KNN;
      float s = 0.f;
#pragma unroll
      for (int j = 0; j < KNN; j++) s += h1b[nb[j]*64 + k];
      X[r*129 + 64 + k] = s;
    }

    int rg = t >> 5, cgi = t & 31;
    float acc[4][4];
#pragma unroll
    for (int r = 0; r < 4; r++)
#pragma unroll
      for (int u = 0; u < 4; u++) acc[r][u] = 0.f;

    const float* wsrc[4] = { a.g2wr, a.g2wr + 32*128, a.g2wl, a.g2wl + 32*128 };
#pragma unroll 1
    for (int ch = 0; ch < 4; ch++) {
      __syncthreads();
      const float* ws = wsrc[ch];
#pragma unroll
      for (int p = 0; p < 16; p++) {
        int idx = t + 256*p;
        Wt[idx] = ws[idx];
      }
      __syncthreads();
      int kb = ch * 32;
      const float* xr0 = X + (rg*4+0)*129 + kb;
      const float* xr1 = X + (rg*4+1)*129 + kb;
      const float* xr2 = X + (rg*4+2)*129 + kb;
      const float* xr3 = X + (rg*4+3)*129 + kb;
#pragma unroll 4
      for (int k = 0; k < 32; k++) {
        float4 w4 = *(const float4*)(Wt + k*128 + cgi*4);
        float x0 = xr0[k], x1 = xr1[k], x2 = xr2[k], x3 = xr3[k];
        acc[0][0] += x0*w4.x; acc[0][1] += x0*w4.y; acc[0][2] += x0*w4.z; acc[0][3] += x0*w4.w;
        acc[1][0] += x1*w4.x; acc[1][1] += x1*w4.y; acc[1][2] += x1*w4.z; acc[1][3] += x1*w4.w;
        acc[2][0] += x2*w4.x; acc[2][1] += x2*w4.y; acc[2][2] += x2*w4.z; acc[2][3] += x2*w4.w;
        acc[3][0] += x3*w4.x; acc[3][1] += x3*w4.y; acc[3][2] += x3*w4.z; acc[3][3] += x3*w4.w;
      }
    }
#pragma unroll
    for (int u = 0; u < 4; u++)
      mred[rg*128 + cgi*4 + u] =
        fmaxf(fmaxf(acc[0][u], acc[1][u]), fmaxf(acc[2][u], acc[3][u]));
    __syncthreads();
    if (t < 128) {
      float mx = mred[t];
#pragma unroll
      for (int g = 1; g < 8; g++) mx = fmaxf(mx, mred[g*128 + t]);
      stg_f(&a.pmax[(size_t)(b*16 + chunk)*128 + t], mx + a.g2b[t]);
    }
  }
  gbar(a.bar, 0, blk);

  // ------- phase 2: proxy max (LDS) + kv slice (32 blocks x 12 outputs) ------
  if (blk < 32) {
    int o0 = blk * 12;
    float* proxy = smem;                 // [32][129]
    for (int i = t; i < 4096; i += 256) {
      int b = i >> 7, c = i & 127;
      float m = -3e38f;
#pragma unroll 4
      for (int ch = 0; ch < 16; ch++)
        m = fmaxf(m, a.pmax[(size_t)(b*16 + ch)*128 + c]);
      proxy[b*129 + c] = m;
    }
    __syncthreads();
#pragma unroll
    for (int rep = 0; rep < 2; rep++) {
      int p = t + rep*256;
      if (p < 32*12) {
        int b = p / 12, o = o0 + p % 12;
        float acc = a.projb[o];
        const float* pr = proxy + b*129;
        for (int s = 0; s < 128; s++) acc += pr[s] * a.projw[s*CC + o];
        stg_f(&a.kv[b*CC + o], acc);
      }
    }
  }
  gbar(a.bar, 1, blk);

  // ---------------- phase 3: vv = kv @ wv.T + bv (48 blocks x 8) -------------
  if (blk < 48) {
    int o0 = blk * 8, b = t >> 3, o = o0 + (t & 7);
    float acc = matvec8(a.kv, CC, a.aiw + (size_t)(2*CC)*CC, CC, o, b, CC/4);
    stg_f(&a.vv[b*CC + o], acc + a.aib[2*CC + o]);
  }
  gbar(a.bar, 2, blk);

  // ---------------- phase 4: q = vv @ aow.T + aob -> xcat[:,1024:] -----------
  if (blk < 48) {
    int o0 = blk * 8, b = t >> 3, o = o0 + (t & 7);
    float acc = matvec8(a.vv, CC, a.aow, CC, o, b, CC/4);
    stg_f(&a.xcat[b*1408 + 1024 + o], acc + a.aob[o]);
  }
  gbar(a.bar, 3, blk);

  // ---------------- phase 5: y = BN(leaky(inc1(q))) (128 blocks x 8) ---------
  if (blk < 128) {
    int o0 = blk * 8, b = t >> 3, o = o0 + (t & 7);
    float acc = matvec8(a.xcat + 1024, 1408, a.i1w, CC, o, b, CC/4);
    float v = acc + a.i1b[o];
    float z = a.bng[o] * (v - a.bnm[o]) * rsqrtf(a.bnv[o] + 1e-5f) + a.bnb[o];
    stg_f(&a.y[b*1024 + o], (z >= 0.f) ? z : 0.2f * z);
  }
  gbar(a.bar, 4, blk);

  // ---------------- phase 6: g2 = inc2(y) -> xcat[:,0:1024] (128 x 8) --------
  if (blk < 128) {
    int o0 = blk * 8, b = t >> 3, o = o0 + (t & 7);
    float acc = matvec8(a.y, 1024, a.i2w, 1024, o, b, 1024/4);
    stg_f(&a.xcat[b*1408 + o], acc + a.i2b[o]);
  }
  gbar(a.bar, 5, blk);

  // ---------------- phase 7: basep = xcat @ red_w[:1408] (48 blocks) ---------
  if (blk < 48) {
    int o0 = blk * 8;
    float* xs = smem;           // [32][129] chunk of xcat (cached loads)
    float* wt = smem + 4128;    // [128][8]  chunk of red_w
    int o4 = t & 1, bb = (t >> 1) & 31, kq = t >> 6;
    float acc0 = 0.f, acc1 = 0.f, acc2 = 0.f, acc3 = 0.f;
#pragma unroll 1
    for (int c0 = 0; c0 < 1408; c0 += 128) {
      __syncthreads();
#pragma unroll
      for (int p = 0; p < 16; p++) {
        int idx = t + 256*p;                    // 4096 = 32 b x 128 k
        xs[(idx >> 7)*129 + (idx & 127)] = a.xcat[(idx >> 7)*1408 + c0 + (idx & 127)];
      }
#pragma unroll
      for (int p = 0; p < 4; p++) {
        int idx = t + 256*p;                    // 1024 = 128 k x 8 o
        wt[idx] = a.redw[(size_t)(c0 + (idx >> 3)) * CC + o0 + (idx & 7)];
      }
      __syncthreads();
      const float* xrow = xs + bb*129 + kq*32;  // conflict-free (stride 129)
      const float* wrow = wt + kq*32*8 + o4*4;  // 2 distinct addrs/wave: broadcast
#pragma unroll 8
      for (int i = 0; i < 32; i++) {
        float  x  = xrow[i];
        float4 w4 = *(const float4*)(wrow + i*8);
        acc0 += x*w4.x; acc1 += x*w4.y; acc2 += x*w4.z; acc3 += x*w4.w;
      }
    }
    __syncthreads();
    float* red = smem;          // [256 threads][4]
    red[t*4+0] = acc0; red[t*4+1] = acc1; red[t*4+2] = acc2; red[t*4+3] = acc3;
    __syncthreads();
    {
      int bb2 = t >> 3, oj = t & 7;            // 32 b x 8 o
      float s = 0.f;
#pragma unroll
      for (int k2 = 0; k2 < 4; k2++)
        s += red[(k2*64 + bb2*2 + (oj >> 2))*4 + (oj & 3)];
      stg_f(&a.basep[bb2*CC + o0 + oj], s);
    }
  }
  gbar(a.bar, 6, blk);

  // ----- phase 8: out = basep + red_b + coarse @ red_w[1408:] (512 blocks) ---
  {
    int b = blk >> 4, mg = blk & 15;            // 16 blocks/batch, 28 rows each
    for (int i = t; i < CC; i += 256) smem[i] = a.basep[b*CC + i];
    __syncthreads();
    const int m0 = mg * 28;
    for (int i = t; i < 28*96; i += 256) {
      int mr = i / 96, c4 = i - mr*96;
      int row = b*MM + m0 + mr;
      int c = c4 * 4;
      float4 p0 = *(const float4*)(smem + c);
      float4 rb = *(const float4*)(a.redb + c);
      const float* cr = a.coarse + (size_t)row * 3;
      float cx = cr[0], cy = cr[1], cz = cr[2];
      float4 w0 = *(const float4*)(a.redw + (size_t)1408*CC + c);
      float4 w1 = *(const float4*)(a.redw + (size_t)1409*CC + c);
      float4 w2 = *(const float4*)(a.redw + (size_t)1410*CC + c);
      float4 o4v;
      o4v.x = p0.x + rb.x + cx*w0.x + cy*w1.x + cz*w2.x;
      o4v.y = p0.y + rb.y + cx*w0.y + cy*w1.y + cz*w2.y;
      o4v.z = p0.z + rb.z + cx*w0.z + cy*w1.z + cz*w2.z;
      o4v.w = p0.w + rb.w + cx*w0.w + cy*w1.w + cz*w2.w;
      *(float4*)(a.out + (size_t)row*CC + c) = o4v;
    }
  }
}

extern "C" void kernel_launch(void* const* d_in, const int* in_sizes, int n_in,
                              void* d_out, int out_size, void* d_ws, size_t ws_size,
                              hipStream_t stream)
{
  (void)in_sizes; (void)n_in; (void)out_size; (void)ws_size;
  // d_in[0] is q (B,M,C): provably unused — attention softmax is uniform.
  const float* coarse = (const float*)d_in[1];
  const float* skel   = (const float*)d_in[2];
  const float* g1wr   = (const float*)d_in[3];
  const float* g1wl   = (const float*)d_in[4];
  const float* g1b    = (const float*)d_in[5];

  char* ws = (char*)d_ws;
  int*      idx_ws = (int*)(ws + WS_IDX);
  float*    h1_ws  = (float*)(ws + WS_H1);
  unsigned* bar    = (unsigned*)(ws + WS_BAR);

  CoopArgs a;
  a.h1    = h1_ws;
  a.idx   = idx_ws;
  a.g2wr  = (const float*)d_in[6];
  a.g2wl  = (const float*)d_in[7];
  a.g2b   = (const float*)d_in[8];
  a.projw = (const float*)d_in[9];
  a.projb = (const float*)d_in[10];
  a.aiw   = (const float*)d_in[11];
  a.aib   = (const float*)d_in[12];
  a.aow   = (const float*)d_in[13];
  a.aob   = (const float*)d_in[14];
  a.i1w   = (const float*)d_in[15];
  a.i1b   = (const float*)d_in[16];
  a.bng   = (const float*)d_in[17];
  a.bnb   = (const float*)d_in[18];
  a.bnm   = (const float*)d_in[19];
  a.bnv   = (const float*)d_in[20];
  a.i2w   = (const float*)d_in[21];
  a.i2b   = (const float*)d_in[22];
  a.redw  = (const float*)d_in[23];
  a.redb  = (const float*)d_in[24];
  a.coarse= coarse;
  a.pmax  = (float*)(ws + WS_PMAX);
  a.kv    = (float*)(ws + WS_KV);
  a.vv    = (float*)(ws + WS_VV);
  a.y     = (float*)(ws + WS_Y);
  a.xcat  = (float*)(ws + WS_XCAT);
  a.basep = (float*)(ws + WS_BASEP);
  a.out   = (float*)d_out;
  a.bar   = bar;

  k_knn_gc1<<<4096, 256, 0, stream>>>(skel, g1wr, g1wl, g1b, idx_ws, h1_ws, bar);
  k_fused<<<NBLK, 256, 0, stream>>>(a);
}

// Round 10
// 282.438 us; speedup vs baseline: 2.0544x; 1.1832x over previous
//
#include <hip/hip_runtime.h>

#define NB 32      // batches
#define MM 448
#define CC 384
#define SS 512
#define KNN 8

// workspace byte offsets (no reuse; ws is 256 MB)
#define WS_IDX    0u            // int   idx[32][512][8]   = 512 KB
#define WS_H1     524288u       // float h1[32][512][64]   = 4 MB
#define WS_PMAX   4718592u      // float pmax[32*16][128]  = 256 KB
#define WS_VV     4980736u      // float vv[32][384]       = 48 KB
#define WS_Q      5029888u      // float q[32][384]        = 48 KB
#define WS_Y      5079040u      // float y[32][1024]       = 128 KB
#define WS_G2     5210112u      // float g2[32][1024]      = 128 KB
#define WS_BASEP  5341184u      // float basep[32][384]    = 48 KB

__device__ __forceinline__ float wave_sum(float v) {
#pragma unroll
  for (int m = 1; m < 64; m <<= 1) v += __shfl_xor(v, m, 64);
  return v;
}

// ------------------------------------------------- K1: KNN + gc1, wave-per-point
__global__ __launch_bounds__(256) void k_knn_gc1(
    const float* __restrict__ skel,
    const float* __restrict__ w1root, const float* __restrict__ w1rel,
    const float* __restrict__ b1,
    int* __restrict__ idx_ws, float* __restrict__ h1_ws)
{
  int b   = blockIdx.x >> 7;          // 128 groups of 4 points per batch
  int grp = blockIdx.x & 127;
  __shared__ __align__(16) float4 sk[SS];
  const float* sb = skel + b * SS * 3;
  for (int t = threadIdx.x; t < SS; t += 256)
    sk[t] = make_float4(sb[t*3+0], sb[t*3+1], sb[t*3+2], 0.f);
  __syncthreads();

  int wave = threadIdx.x >> 6, lane = threadIdx.x & 63;
  int i = grp * 4 + wave;             // this wave's point
  float4 pi = sk[i];

  float bd[KNN];
#pragma unroll
  for (int t = 0; t < KNN; t++) {
    int j = lane + (t << 6);
    float4 p = sk[j];
    float d2;
    {
#pragma clang fp contract(off)
      float dx = pi.x - p.x, dy = pi.y - p.y, dz = pi.z - p.z;
      d2 = (dx*dx + dy*dy) + dz*dz;
    }
    bd[t] = (j == i) ? 3e38f : d2;
  }

  int win[KNN];
  int* idx_base = idx_ws + (size_t)(b*SS + i) * KNN;
#pragma unroll
  for (int t = 0; t < KNN; t++) {
    float bestd = bd[0]; int bests = 0;
#pragma unroll
    for (int s = 1; s < KNN; s++)
      if (bd[s] < bestd) { bestd = bd[s]; bests = s; }
    int bestj = lane + (bests << 6);
#pragma unroll
    for (int m = 1; m < 64; m <<= 1) {
      float od = __shfl_xor(bestd, m, 64);
      int   oj = __shfl_xor(bestj, m, 64);
      if (od < bestd || (od == bestd && oj < bestj)) { bestd = od; bestj = oj; }
    }
    win[t] = bestj;
    if (lane == t) idx_base[t] = bestj;
    if ((bestj & 63) == lane) {
      int sl = bestj >> 6;
#pragma unroll
      for (int s = 0; s < KNN; s++) if (s == sl) bd[s] = 3e38f;
    }
  }

  float a0 = 0.f, a1 = 0.f, a2 = 0.f;
#pragma unroll
  for (int t = 0; t < KNN; t++) {
    float4 n = sk[win[t]];
    a0 += n.x; a1 += n.y; a2 += n.z;
  }

  int c = lane;
  float h = b1[c] + pi.x*w1root[c] + pi.y*w1root[64+c] + pi.z*w1root[128+c]
                  + a0*w1rel[c]   + a1*w1rel[64+c]   + a2*w1rel[128+c];
  h = fmaxf(h, 0.f);
  h1_ws[(size_t)(b*SS + i) * 64 + lane] = h;
}

// -------- K2: gc2+max as one GEMM [16384x128]@[128x128], fused agg-gather + max
__global__ __launch_bounds__(256) void k_gc2_max(
    const float* __restrict__ h1_ws, const int* __restrict__ idx_ws,
    const float* __restrict__ w2root, const float* __restrict__ w2rel,
    const float* __restrict__ b2, float* __restrict__ pmax)
{
  int b = blockIdx.x >> 4, chunk = blockIdx.x & 15;
  int r0 = chunk * 32;
  __shared__ __align__(16) float X[32*129];   // [row][k], stride 129
  __shared__ __align__(16) float Wt[32*128];  // k-chunk of stacked W
  __shared__ float mred[8*128];
  __shared__ int nbs[32*KNN];

  const float* h1b = h1_ws + (size_t)b * SS * 64;
  nbs[threadIdx.x] = idx_ws[(b*SS + r0)*KNN + threadIdx.x];   // 256 = 32*8
#pragma unroll
  for (int p = 0; p < 8; p++) {
    int idx = threadIdx.x + 256*p;
    int r = idx >> 6, k = idx & 63;
    X[r*129 + k] = h1b[(r0 + r)*64 + k];
  }
  __syncthreads();   // nbs ready
#pragma unroll
  for (int p = 0; p < 8; p++) {
    int idx = threadIdx.x + 256*p;
    int r = idx >> 6, k = idx & 63;
    const int* nb = nbs + r*KNN;
    float s = 0.f;
#pragma unroll
    for (int j = 0; j < KNN; j++) s += h1b[nb[j]*64 + k];
    X[r*129 + 64 + k] = s;
  }

  int rg = threadIdx.x >> 5, cg = threadIdx.x & 31;
  float acc[4][4];
#pragma unroll
  for (int r = 0; r < 4; r++)
#pragma unroll
    for (int u = 0; u < 4; u++) acc[r][u] = 0.f;

  const float* wsrc[4] = { w2root, w2root + 32*128, w2rel, w2rel + 32*128 };
#pragma unroll 1
  for (int ch = 0; ch < 4; ch++) {
    __syncthreads();
    const float* ws = wsrc[ch];
#pragma unroll
    for (int p = 0; p < 16; p++) {
      int idx = threadIdx.x + 256*p;
      Wt[idx] = ws[idx];                 // coalesced
    }
    __syncthreads();
    int kb = ch * 32;
    const float* xr0 = X + (rg*4+0)*129 + kb;
    const float* xr1 = X + (rg*4+1)*129 + kb;
    const float* xr2 = X + (rg*4+2)*129 + kb;
    const float* xr3 = X + (rg*4+3)*129 + kb;
#pragma unroll 4
    for (int k = 0; k < 32; k++) {
      float4 w4 = *(const float4*)(Wt + k*128 + cg*4);
      float x0 = xr0[k], x1 = xr1[k], x2 = xr2[k], x3 = xr3[k];
      acc[0][0] += x0*w4.x; acc[0][1] += x0*w4.y; acc[0][2] += x0*w4.z; acc[0][3] += x0*w4.w;
      acc[1][0] += x1*w4.x; acc[1][1] += x1*w4.y; acc[1][2] += x1*w4.z; acc[1][3] += x1*w4.w;
      acc[2][0] += x2*w4.x; acc[2][1] += x2*w4.y; acc[2][2] += x2*w4.z; acc[2][3] += x2*w4.w;
      acc[3][0] += x3*w4.x; acc[3][1] += x3*w4.y; acc[3][2] += x3*w4.z; acc[3][3] += x3*w4.w;
    }
  }
#pragma unroll
  for (int u = 0; u < 4; u++)
    mred[rg*128 + cg*4 + u] =
      fmaxf(fmaxf(acc[0][u], acc[1][u]), fmaxf(acc[2][u], acc[3][u]));
  __syncthreads();
  if (threadIdx.x < 128) {
    int col = threadIdx.x;
    float mx = mred[col];
#pragma unroll
    for (int g = 1; g < 8; g++) mx = fmaxf(mx, mred[g*128 + col]);
    pmax[(size_t)(b*16 + chunk)*128 + col] = mx + b2[col];
  }
}

// ----- K3: proxy max + kv (in-LDS, dup x12) + vv slice — 384 blocks (32b x 12og)
// fuses baseline k_proxy_kv + k_mv384(vv): one dispatch + one gap saved
__global__ __launch_bounds__(256) void k_chain1(
    const float* __restrict__ pmax,
    const float* __restrict__ proj_w, const float* __restrict__ proj_b,
    const float* __restrict__ aiw, const float* __restrict__ aib,
    float* __restrict__ vv_ws)
{
  int b = blockIdx.x & 31, og = blockIdx.x >> 5;   // og 0..11
  __shared__ float proxy[128];
  __shared__ float kv[CC];
  int t = threadIdx.x;
  if (t < 128) {
    float m = -3e38f;
    const float* pm = pmax + (size_t)b*2048 + t;
#pragma unroll
    for (int ch = 0; ch < 16; ch++) m = fmaxf(m, pm[ch*128]);
    proxy[t] = m;
  }
  __syncthreads();
  for (int o = t; o < CC; o += 256) {              // kv full, o-coalesced
    float acc = proj_b[o];
#pragma unroll 8
    for (int k = 0; k < 128; k++) acc += proxy[k] * proj_w[k*CC + o];
    kv[o] = acc;
  }
  __syncthreads();
  int wv = t >> 6, lane = t & 63;
  float x0 = kv[lane*6+0], x1 = kv[lane*6+1], x2 = kv[lane*6+2];
  float x3 = kv[lane*6+3], x4 = kv[lane*6+4], x5 = kv[lane*6+5];
#pragma unroll
  for (int u = 0; u < 8; u++) {
    int o = og*32 + wv*8 + u;
    const float* wr = aiw + (size_t)(2*CC + o) * CC + lane*6;
    float2 wa = *(const float2*)wr;
    float2 wb = *(const float2*)(wr + 2);
    float2 wc = *(const float2*)(wr + 4);
    float p = wa.x*x0 + wa.y*x1 + wb.x*x2 + wb.y*x3 + wc.x*x4 + wc.y*x5;
    p = wave_sum(p);
    if (lane == 0) vv_ws[b*CC + o] = aib[2*CC + o] + p;
  }
}

// ------------------------- K4: generic 384->384 matvec, wave-per-output dot
__global__ __launch_bounds__(256) void k_mv384(
    const float* __restrict__ xin, const float* __restrict__ w, int row0,
    const float* __restrict__ bias, int bias0, float* __restrict__ out)
{
  int b = blockIdx.x, og = blockIdx.y;
  int wv = threadIdx.x >> 6, lane = threadIdx.x & 63;
  __shared__ float xs[CC];
  for (int t = threadIdx.x; t < CC; t += 256) xs[t] = xin[b*CC + t];
  __syncthreads();
  float x0 = xs[lane*6+0], x1 = xs[lane*6+1], x2 = xs[lane*6+2];
  float x3 = xs[lane*6+3], x4 = xs[lane*6+4], x5 = xs[lane*6+5];
#pragma unroll
  for (int u = 0; u < 8; u++) {
    int o = og*32 + wv*8 + u;
    const float* wr = w + (size_t)(row0 + o) * CC + lane*6;
    float2 wa = *(const float2*)wr;
    float2 wb = *(const float2*)(wr + 2);
    float2 wc = *(const float2*)(wr + 4);
    float p = wa.x*x0 + wa.y*x1 + wb.x*x2 + wb.y*x3 + wc.x*x4 + wc.y*x5;
    p = wave_sum(p);
    if (lane == 0) out[b*CC + o] = bias[bias0 + o] + p;
  }
}

// ---------- K5: inc1 + BN + leaky. 4 lanes per output, contiguous quarter-rows.
__global__ __launch_bounds__(256) void k_inc1_bn(
    const float* __restrict__ q_ws, const float* __restrict__ inc1_w,
    const float* __restrict__ inc1_b,
    const float* __restrict__ bng, const float* __restrict__ bnb,
    const float* __restrict__ bnm, const float* __restrict__ bnv,
    float* __restrict__ y_ws)
{
  int b = blockIdx.x >> 4, og = blockIdx.x & 15;
  int t = threadIdx.x;
  int o = og*64 + (t >> 2), qq = t & 3;
  __shared__ __align__(16) float xs[CC];
  for (int i = t; i < CC; i += 256) xs[i] = q_ws[b*CC + i];
  __syncthreads();
  const float* wr = inc1_w + (size_t)o * CC + qq*96;
  const float* xr = xs + qq*96;
  float acc = 0.f;
#pragma unroll
  for (int kk = 0; kk < 96; kk += 4) {
    float4 w4 = *(const float4*)(wr + kk);
    float4 x4 = *(const float4*)(xr + kk);
    acc += w4.x*x4.x + w4.y*x4.y + w4.z*x4.z + w4.w*x4.w;
  }
  acc += __shfl_xor(acc, 1, 64);
  acc += __shfl_xor(acc, 2, 64);
  if (qq == 0) {
    float a = acc + inc1_b[o];
    float z = bng[o] * (a - bnm[o]) * rsqrtf(bnv[o] + 1e-5f) + bnb[o];
    y_ws[b*1024 + o] = (z >= 0.f) ? z : 0.2f * z;
  }
}

// ---------------- K6: inc2. 4 lanes per output, contiguous quarter-rows (K=1024).
__global__ __launch_bounds__(256) void k_inc2(
    const float* __restrict__ y_ws, const float* __restrict__ inc2_w,
    const float* __restrict__ inc2_b, float* __restrict__ g2_ws)
{
  int b = blockIdx.x >> 4, og = blockIdx.x & 15;
  int t = threadIdx.x;
  int o = og*64 + (t >> 2), qq = t & 3;
  __shared__ __align__(16) float xs[1024];
  for (int i = t; i < 1024; i += 256) xs[i] = y_ws[b*1024 + i];
  __syncthreads();
  const float* wr = inc2_w + (size_t)o * 1024 + qq*256;
  const float* xr = xs + qq*256;
  float acc = 0.f;
#pragma unroll 8
  for (int kk = 0; kk < 256; kk += 4) {
    float4 w4 = *(const float4*)(wr + kk);
    float4 x4 = *(const float4*)(xr + kk);
    acc += w4.x*x4.x + w4.y*x4.y + w4.z*x4.z + w4.w*x4.w;
  }
  acc += __shfl_xor(acc, 1, 64);
  acc += __shfl_xor(acc, 2, 64);
  if (qq == 0) g2_ws[b*1024 + o] = acc + inc2_b[o];
}

// ----- K7: basep = [g2|q] @ red_w[:1408] — 48 blocks, full-K in registers.
// merges baseline k_basep + k_base_red (no pp buffer, one fewer dispatch);
// inner logic identical to the verified R6/R9 phase-7.
__global__ __launch_bounds__(256) void k_basep_full(
    const float* __restrict__ g2_ws, const float* __restrict__ q_ws,
    const float* __restrict__ red_w, float* __restrict__ basep)
{
  int o0 = blockIdx.x * 8;
  __shared__ __align__(16) float xs[32*129];   // [b][k-chunk], stride 129
  __shared__ __align__(16) float wt[128*8];    // [k][o]
  int t = threadIdx.x;
  int o4 = t & 1, bb = (t >> 1) & 31, kq = t >> 6;
  float acc0 = 0.f, acc1 = 0.f, acc2 = 0.f, acc3 = 0.f;
#pragma unroll 1
  for (int c0 = 0; c0 < 1408; c0 += 128) {
    __syncthreads();
    const float* src = (c0 < 1024) ? (g2_ws + c0) : (q_ws + (c0 - 1024));
    int stride = (c0 < 1024) ? 1024 : CC;
#pragma unroll
    for (int p = 0; p < 16; p++) {
      int idx = t + 256*p;                    // 4096 = 32 b x 128 k
      int b = idx >> 7, k = idx & 127;
      xs[b*129 + k] = src[(size_t)b*stride + k];
    }
#pragma unroll
    for (int p = 0; p < 4; p++) {
      int idx = t + 256*p;                    // 1024 = 128 k x 8 o
      wt[idx] = red_w[(size_t)(c0 + (idx >> 3)) * CC + o0 + (idx & 7)];
    }
    __syncthreads();
    const float* xrow = xs + bb*129 + kq*32;  // conflict-free (stride 129)
    const float* wrow = wt + kq*32*8 + o4*4;  // 2 distinct addrs/wave: broadcast
#pragma unroll 8
    for (int i = 0; i < 32; i++) {
      float  x  = xrow[i];
      float4 w4 = *(const float4*)(wrow + i*8);
      acc0 += x*w4.x; acc1 += x*w4.y; acc2 += x*w4.z; acc3 += x*w4.w;
    }
  }
  __syncthreads();
  float* red = xs;            // [256 threads][4]
  red[t*4+0] = acc0; red[t*4+1] = acc1; red[t*4+2] = acc2; red[t*4+3] = acc3;
  __syncthreads();
  {
    int bb2 = t >> 3, oj = t & 7;            // 32 b x 8 o
    float s = 0.f;
#pragma unroll
    for (int k2 = 0; k2 < 4; k2++)
      s += red[(k2*64 + bb2*2 + (oj >> 2))*4 + (oj & 3)];
    basep[bb2*CC + o0 + oj] = s;
  }
}

// --------------------------------------------- K8: out = base + coarse @ red_w3
__global__ __launch_bounds__(256) void k_out(
    const float* __restrict__ basep, const float* __restrict__ red_b,
    const float* __restrict__ red_w, const float* __restrict__ coarse,
    float* __restrict__ out)
{
  int gid = blockIdx.x * 256 + threadIdx.x;   // < 32*448*96 exactly
  int c4 = gid % 96;
  int row = gid / 96;                          // b*448 + m
  int b = row / 448;
  int c = c4 * 4;
  float4 p0 = *(const float4*)(basep + b*CC + c);
  float4 rb = *(const float4*)(red_b + c);
  const float* cr = coarse + (size_t)row * 3;
  float cx = cr[0], cy = cr[1], cz = cr[2];
  float4 w0 = *(const float4*)(red_w + (size_t)1408*CC + c);
  float4 w1 = *(const float4*)(red_w + (size_t)1409*CC + c);
  float4 w2 = *(const float4*)(red_w + (size_t)1410*CC + c);
  float4 o4;
  o4.x = p0.x + rb.x + cx*w0.x + cy*w1.x + cz*w2.x;
  o4.y = p0.y + rb.y + cx*w0.y + cy*w1.y + cz*w2.y;
  o4.z = p0.z + rb.z + cx*w0.z + cy*w1.z + cz*w2.z;
  o4.w = p0.w + rb.w + cx*w0.w + cy*w1.w + cz*w2.w;
  *(float4*)(out + (size_t)row*CC + c) = o4;
}

extern "C" void kernel_launch(void* const* d_in, const int* in_sizes, int n_in,
                              void* d_out, int out_size, void* d_ws, size_t ws_size,
                              hipStream_t stream)
{
  (void)in_sizes; (void)n_in; (void)out_size; (void)ws_size;
  // d_in[0] is q (B,M,C): provably unused — attention softmax is uniform.
  const float* coarse = (const float*)d_in[1];
  const float* skel   = (const float*)d_in[2];
  const float* g1wr   = (const float*)d_in[3];
  const float* g1wl   = (const float*)d_in[4];
  const float* g1b    = (const float*)d_in[5];
  const float* g2wr   = (const float*)d_in[6];
  const float* g2wl   = (const float*)d_in[7];
  const float* g2b    = (const float*)d_in[8];
  const float* projw  = (const float*)d_in[9];
  const float* projb  = (const float*)d_in[10];
  const float* aiw    = (const float*)d_in[11];
  const float* aib    = (const float*)d_in[12];
  const float* aow    = (const float*)d_in[13];
  const float* aob    = (const float*)d_in[14];
  const float* i1w    = (const float*)d_in[15];
  const float* i1b    = (const float*)d_in[16];
  const float* bng    = (const float*)d_in[17];
  const float* bnb    = (const float*)d_in[18];
  const float* bnm    = (const float*)d_in[19];
  const float* bnv    = (const float*)d_in[20];
  const float* i2w    = (const float*)d_in[21];
  const float* i2b    = (const float*)d_in[22];
  const float* redw   = (const float*)d_in[23];
  const float* redb   = (const float*)d_in[24];
  float* out = (float*)d_out;

  char* ws = (char*)d_ws;
  int*   idx_ws = (int*)(ws + WS_IDX);
  float* h1_ws  = (float*)(ws + WS_H1);
  float* pmax   = (float*)(ws + WS_PMAX);
  float* vv_ws  = (float*)(ws + WS_VV);
  float* q_ws   = (float*)(ws + WS_Q);
  float* y_ws   = (float*)(ws + WS_Y);
  float* g2_ws  = (float*)(ws + WS_G2);
  float* basep  = (float*)(ws + WS_BASEP);

  k_knn_gc1<<<4096, 256, 0, stream>>>(skel, g1wr, g1wl, g1b, idx_ws, h1_ws);
  k_gc2_max<<<512, 256, 0, stream>>>(h1_ws, idx_ws, g2wr, g2wl, g2b, pmax);
  k_chain1<<<384, 256, 0, stream>>>(pmax, projw, projb, aiw, aib, vv_ws);
  k_mv384<<<dim3(32, 12), 256, 0, stream>>>(vv_ws, aow, 0, aob, 0, q_ws);  // q
  k_inc1_bn<<<512, 256, 0, stream>>>(q_ws, i1w, i1b, bng, bnb, bnm, bnv, y_ws);
  k_inc2<<<512, 256, 0, stream>>>(y_ws, i2w, i2b, g2_ws);
  k_basep_full<<<48, 256, 0, stream>>>(g2_ws, q_ws, redw, basep);
  k_out<<<5376, 256, 0, stream>>>(basep, redb, redw, coarse, out);
}